// Round 6
// baseline (1295.674 us; speedup 1.0000x reference)
//
#include <hip/hip_runtime.h>

static constexpr int BTRIALS = 32;
static constexpr int TSTEPS  = 512;
static constexpr int IDIM    = 64;
static constexpr int NDIM    = 4096;
static constexpr int RDIM    = 8;
static constexpr int ODIM    = 64;

typedef short v8s __attribute__((ext_vector_type(8)));
typedef float v4f __attribute__((ext_vector_type(4)));

__device__ __forceinline__ float fast_sigmoid(float x) {
    float e = __builtin_amdgcn_exp2f(x * -1.44269504088896340736f);
    return __builtin_amdgcn_rcpf(1.0f + e);
}

// v += dpp_move(v), 0-fill invalid lanes
template <int CTRL, int RMASK>
__device__ __forceinline__ float dpp_add(float v) {
    int moved = __builtin_amdgcn_update_dpp(0, __float_as_int(v), CTRL, RMASK, 0xf, true);
    return v + __int_as_float(moved);
}

// full 64-lane sum -> valid in lane 63
__device__ __forceinline__ float wave_reduce_to_lane63(float v) {
    v = dpp_add<0x111, 0xf>(v);  // row_shr:1
    v = dpp_add<0x112, 0xf>(v);  // row_shr:2
    v = dpp_add<0x114, 0xf>(v);  // row_shr:4
    v = dpp_add<0x118, 0xf>(v);  // row_shr:8
    v = dpp_add<0x142, 0xa>(v);  // row_bcast:15 -> rows 1,3
    v = dpp_add<0x143, 0xc>(v);  // row_bcast:31 -> rows 2,3
    return v;
}

__device__ __forceinline__ short f2bf(float f) {
    unsigned u = __float_as_uint(f);
    u += 0x7FFFu + ((u >> 16) & 1u);   // RNE
    return (short)(u >> 16);
}

// ---------------------------------------------------------------------------
// Split fp32 stream into bf16 hi/lo pair (optionally pre-scaled).
// ---------------------------------------------------------------------------
__global__ __launch_bounds__(256) void split_conv(const float* __restrict__ src,
                                                  unsigned short* __restrict__ hi,
                                                  unsigned short* __restrict__ lo,
                                                  float scale) {
    const int base = (blockIdx.x * 256 + threadIdx.x) * 8;
    float4 a = *(const float4*)(src + base);
    float4 b = *(const float4*)(src + base + 4);
    float v[8] = {a.x, a.y, a.z, a.w, b.x, b.y, b.z, b.w};
    v8s h, l;
    #pragma unroll
    for (int j = 0; j < 8; ++j) {
        float f  = v[j] * scale;
        short hb = f2bf(f);
        h[j] = hb;
        float fh = __uint_as_float(((unsigned)(unsigned short)hb) << 16);
        l[j] = f2bf(f - fh);
    }
    *(v8s*)(hi + base) = h;
    *(v8s*)(lo + base) = l;
}

// ---------------------------------------------------------------------------
// W fp32 -> bf16, once.
// ---------------------------------------------------------------------------
__global__ __launch_bounds__(256) void wconv(const float* __restrict__ W,
                                             unsigned short* __restrict__ Wb) {
    const int base = (blockIdx.x * 256 + threadIdx.x) * 8;
    float4 a = *(const float4*)(W + base);
    float4 b = *(const float4*)(W + base + 4);
    v8s o;
    o[0] = f2bf(a.x); o[1] = f2bf(a.y); o[2] = f2bf(a.z); o[3] = f2bf(a.w);
    o[4] = f2bf(b.x); o[5] = f2bf(b.y); o[6] = f2bf(b.z); o[7] = f2bf(b.w);
    *(v8s*)(Wb + base) = o;
}

// ---------------------------------------------------------------------------
// Phase 1 (MFMA): u = (DT*inp) @ B^T via bf16x3 split arithmetic. Unchanged.
// ---------------------------------------------------------------------------
__global__ __launch_bounds__(256) void pre_gemm_mfma(const unsigned short* __restrict__ Ah,
                                                     const unsigned short* __restrict__ Al,
                                                     const unsigned short* __restrict__ Bh,
                                                     const unsigned short* __restrict__ Bl,
                                                     float* __restrict__ u, int t0) {
    const int tid  = threadIdx.x;
    const int lane = tid & 63;
    const int wv   = tid >> 6;          // 0..3
    const int lm   = lane & 15;
    const int kq   = lane >> 4;         // 0..3

    const int mloc = blockIdx.x * 16 + lm;        // u row (tl*32+b)
    const int b    = mloc & 31;
    const int t    = t0 + (mloc >> 5);
    const size_t arow = (size_t)b * TSTEPS + t;

    const unsigned short* pah = Ah + arow * IDIM + kq * 8;
    const unsigned short* pal = Al + arow * IDIM + kq * 8;
    v8s ah0 = *(const v8s*)(pah);
    v8s ah1 = *(const v8s*)(pah + 32);
    v8s al0 = *(const v8s*)(pal);
    v8s al1 = *(const v8s*)(pal + 32);

    const int n0   = wv * 1024;
    const int urow = blockIdx.x * 16 + kq * 4;

    #pragma unroll 2
    for (int nt = 0; nt < 64; ++nt) {
        const int n = n0 + nt * 16 + lm;
        const unsigned short* pbh = Bh + (size_t)n * IDIM + kq * 8;
        const unsigned short* pbl = Bl + (size_t)n * IDIM + kq * 8;
        v8s bh0 = *(const v8s*)(pbh);
        v8s bh1 = *(const v8s*)(pbh + 32);
        v8s bl0 = *(const v8s*)(pbl);
        v8s bl1 = *(const v8s*)(pbl + 32);
        v4f acc = (v4f){0.f, 0.f, 0.f, 0.f};
        acc = __builtin_amdgcn_mfma_f32_16x16x32_bf16(ah0, bl0, acc, 0, 0, 0);
        acc = __builtin_amdgcn_mfma_f32_16x16x32_bf16(al0, bh0, acc, 0, 0, 0);
        acc = __builtin_amdgcn_mfma_f32_16x16x32_bf16(ah1, bl1, acc, 0, 0, 0);
        acc = __builtin_amdgcn_mfma_f32_16x16x32_bf16(al1, bh1, acc, 0, 0, 0);
        acc = __builtin_amdgcn_mfma_f32_16x16x32_bf16(ah0, bh0, acc, 0, 0, 0);
        acc = __builtin_amdgcn_mfma_f32_16x16x32_bf16(ah1, bh1, acc, 0, 0, 0);
        float* up = u + (size_t)urow * NDIM + n0 + nt * 16 + lm;
        #pragma unroll
        for (int r = 0; r < 4; ++r) up[(size_t)r * NDIM] = acc[r];
    }
}

// ---------------------------------------------------------------------------
// Phase 2: serial scan, WRITE-FREE (only ps scalars). 32 blocks x 512 thr.
// Emits ps[b][t][8] (512 KB total); x/sigmoid stay in registers. Depth-2
// u prefetch to double per-CU outstanding read bytes.
// ---------------------------------------------------------------------------
__global__ __launch_bounds__(512, 2) void scan_kernel(const float* __restrict__ mmat,
                                                      const float* __restrict__ nmat,
                                                      const float* __restrict__ u,
                                                      float* __restrict__ xstate,
                                                      float* __restrict__ psbuf,
                                                      int t0, int tc) {
    const int b    = blockIdx.x;
    const int tid  = threadIdx.x;
    const int j0   = tid * 8;
    const int lane = tid & 63;
    const int wv   = tid >> 6;   // 0..7

    __shared__ __align__(16) float wlds[2][64];   // [r*8 + w], double-buffered

    float nm[8][8], mmr[8][8], x[8], s[8];
    const float4* np4 = (const float4*)(nmat + (size_t)j0 * RDIM);
    const float4* mp4 = (const float4*)(mmat + (size_t)j0 * RDIM);
    const float mscale = 0.1f / 4096.0f;   // DT / N folded into m
    #pragma unroll
    for (int j = 0; j < 8; ++j) {
        float4 a = np4[j * 2], c = np4[j * 2 + 1];
        nm[j][0] = a.x; nm[j][1] = a.y; nm[j][2] = a.z; nm[j][3] = a.w;
        nm[j][4] = c.x; nm[j][5] = c.y; nm[j][6] = c.z; nm[j][7] = c.w;
        float4 d = mp4[j * 2], e = mp4[j * 2 + 1];
        mmr[j][0] = d.x * mscale; mmr[j][1] = d.y * mscale;
        mmr[j][2] = d.z * mscale; mmr[j][3] = d.w * mscale;
        mmr[j][4] = e.x * mscale; mmr[j][5] = e.y * mscale;
        mmr[j][6] = e.z * mscale; mmr[j][7] = e.w * mscale;
    }

    if (t0 == 0) {
        #pragma unroll
        for (int j = 0; j < 8; ++j) x[j] = 0.0f;
    } else {
        const float* xs = xstate + (size_t)b * NDIM + j0;
        float4 v0 = *(const float4*)(xs + 0);
        float4 v1 = *(const float4*)(xs + 4);
        x[0] = v0.x; x[1] = v0.y; x[2] = v0.z; x[3] = v0.w;
        x[4] = v1.x; x[5] = v1.y; x[6] = v1.z; x[7] = v1.w;
    }
    #pragma unroll
    for (int j = 0; j < 8; ++j) s[j] = fast_sigmoid(x[j]);

    // u ring: uv = u[t], (p0a,p0b) = u[t+1], (p1a,p1b) = u[t+2]
    float uv[8];
    {
        const float* up = u + ((size_t)0 * BTRIALS + b) * NDIM + j0;
        float4 v0 = *(const float4*)(up + 0);
        float4 v1 = *(const float4*)(up + 4);
        uv[0] = v0.x; uv[1] = v0.y; uv[2] = v0.z; uv[3] = v0.w;
        uv[4] = v1.x; uv[5] = v1.y; uv[6] = v1.z; uv[7] = v1.w;
    }
    const int t1 = (1 < tc) ? 1 : tc - 1;
    const int t2 = (2 < tc) ? 2 : tc - 1;
    const float* up1 = u + ((size_t)t1 * BTRIALS + b) * NDIM + j0;
    const float* up2 = u + ((size_t)t2 * BTRIALS + b) * NDIM + j0;
    float4 p0a = *(const float4*)(up1 + 0);
    float4 p0b = *(const float4*)(up1 + 4);
    float4 p1a = *(const float4*)(up2 + 0);
    float4 p1b = *(const float4*)(up2 + 4);

    for (int tl = 0; tl < tc; ++tl) {
        const int buf = tl & 1;

        // partial projections from carried s
        float part[8];
        #pragma unroll
        for (int r = 0; r < 8; ++r) part[r] = 0.0f;
        #pragma unroll
        for (int j = 0; j < 8; ++j) {
            #pragma unroll
            for (int r = 0; r < 8; ++r) part[r] = fmaf(s[j], nm[j][r], part[r]);
        }
        #pragma unroll
        for (int r = 0; r < 8; ++r) part[r] = wave_reduce_to_lane63(part[r]);

        if (lane == 63) {
            #pragma unroll
            for (int r = 0; r < 8; ++r) wlds[buf][r * 8 + wv] = part[r];
        }

        // decay + input before the barrier
        float xd[8];
        #pragma unroll
        for (int j = 0; j < 8; ++j) xd[j] = fmaf(0.9f, x[j], uv[j]);

        __syncthreads();

        // fold 8 wave-partials per r
        float v = wlds[buf][lane];
        v = dpp_add<0x111, 0xf>(v);  // row_shr:1
        v = dpp_add<0x112, 0xf>(v);  // row_shr:2
        v = dpp_add<0x114, 0xf>(v);  // row_shr:4

        float ps[8];
        #pragma unroll
        for (int r = 0; r < 8; ++r)
            ps[r] = __int_as_float(__builtin_amdgcn_readlane(__float_as_int(v), r * 8 + 7));

        if (tid == 0) {
            float* pp = psbuf + ((size_t)b * TSTEPS + (t0 + tl)) * 8;
            *(float4*)(pp + 0) = make_float4(ps[0], ps[1], ps[2], ps[3]);
            *(float4*)(pp + 4) = make_float4(ps[4], ps[5], ps[6], ps[7]);
        }

        #pragma unroll
        for (int j = 0; j < 8; ++j) {
            float acc = xd[j];
            #pragma unroll
            for (int r = 0; r < 8; ++r) acc = fmaf(ps[r], mmr[j][r], acc);
            x[j] = acc;
        }
        #pragma unroll
        for (int j = 0; j < 8; ++j) s[j] = fast_sigmoid(x[j]);

        // rotate u ring, issue load 3 steps ahead
        uv[0] = p0a.x; uv[1] = p0a.y; uv[2] = p0a.z; uv[3] = p0a.w;
        uv[4] = p0b.x; uv[5] = p0b.y; uv[6] = p0b.z; uv[7] = p0b.w;
        p0a = p1a; p0b = p1b;
        const int tn = (tl + 3 < tc) ? (tl + 3) : (tc - 1);
        const float* upn = u + ((size_t)tn * BTRIALS + b) * NDIM + j0;
        p1a = *(const float4*)(upn + 0);
        p1b = *(const float4*)(upn + 4);
    }

    float* xs = xstate + (size_t)b * NDIM + j0;
    *(float4*)(xs + 0) = make_float4(x[0], x[1], x[2], x[3]);
    *(float4*)(xs + 4) = make_float4(x[4], x[5], x[6], x[7]);
}

// ---------------------------------------------------------------------------
// Phase 2b: x_replay — regenerate xseq (fp32) and sbuf (bf16 sigmoid) from
// u + ps, bit-identical fmaf order to scan. Fully parallel over (b, n):
// grid (8, 32) x 256 thr, 2 neurons/thread, all 256 CUs, full-chip BW.
// ---------------------------------------------------------------------------
__global__ __launch_bounds__(256) void x_replay(const float* __restrict__ mmat,
                                                const float* __restrict__ u,
                                                const float* __restrict__ psbuf,
                                                float* __restrict__ xseq,
                                                unsigned short* __restrict__ sbuf,
                                                int t0, int tc) {
    const int tid = threadIdx.x;
    const int b   = blockIdx.y;
    const int n0  = blockIdx.x * 512 + tid * 2;

    const float mscale = 0.1f / 4096.0f;
    float mm0[8], mm1[8];
    {
        float4 d0 = *(const float4*)(mmat + (size_t)n0 * RDIM);
        float4 d1 = *(const float4*)(mmat + (size_t)n0 * RDIM + 4);
        float4 e0 = *(const float4*)(mmat + (size_t)(n0 + 1) * RDIM);
        float4 e1 = *(const float4*)(mmat + (size_t)(n0 + 1) * RDIM + 4);
        mm0[0] = d0.x * mscale; mm0[1] = d0.y * mscale; mm0[2] = d0.z * mscale; mm0[3] = d0.w * mscale;
        mm0[4] = d1.x * mscale; mm0[5] = d1.y * mscale; mm0[6] = d1.z * mscale; mm0[7] = d1.w * mscale;
        mm1[0] = e0.x * mscale; mm1[1] = e0.y * mscale; mm1[2] = e0.z * mscale; mm1[3] = e0.w * mscale;
        mm1[4] = e1.x * mscale; mm1[5] = e1.y * mscale; mm1[6] = e1.z * mscale; mm1[7] = e1.w * mscale;
    }

    float x0, x1;
    if (t0 == 0) {
        x0 = 0.f; x1 = 0.f;
        *(float2*)(xseq + (size_t)b * (TSTEPS + 1) * NDIM + n0) = make_float2(0.f, 0.f);
    } else {
        float2 v = *(const float2*)(xseq + ((size_t)b * (TSTEPS + 1) + t0) * NDIM + n0);
        x0 = v.x; x1 = v.y;
    }

    // u ring depth 2 + ps prefetch depth 1
    const int t1 = (1 < tc) ? 1 : tc - 1;
    const int t2 = (2 < tc) ? 2 : tc - 1;
    float2 uv = *(const float2*)(u + ((size_t)0 * BTRIALS + b) * NDIM + n0);
    float2 q0 = *(const float2*)(u + ((size_t)t1 * BTRIALS + b) * NDIM + n0);
    float2 q1 = *(const float2*)(u + ((size_t)t2 * BTRIALS + b) * NDIM + n0);
    const float* pp0 = psbuf + ((size_t)b * TSTEPS + t0) * 8;
    float4 psa = *(const float4*)(pp0 + 0);
    float4 psb = *(const float4*)(pp0 + 4);

    for (int tl = 0; tl < tc; ++tl) {
        float ps[8] = {psa.x, psa.y, psa.z, psa.w, psb.x, psb.y, psb.z, psb.w};

        // prefetch next ps
        const int tpn = (tl + 1 < tc) ? (tl + 1) : tl;
        const float* ppn = psbuf + ((size_t)b * TSTEPS + (t0 + tpn)) * 8;
        float4 npa = *(const float4*)(ppn + 0);
        float4 npb = *(const float4*)(ppn + 4);

        float xd0 = fmaf(0.9f, x0, uv.x);
        float xd1 = fmaf(0.9f, x1, uv.y);
        #pragma unroll
        for (int r = 0; r < 8; ++r) xd0 = fmaf(ps[r], mm0[r], xd0);
        #pragma unroll
        for (int r = 0; r < 8; ++r) xd1 = fmaf(ps[r], mm1[r], xd1);
        x0 = xd0; x1 = xd1;

        *(float2*)(xseq + ((size_t)b * (TSTEPS + 1) + (t0 + tl + 1)) * NDIM + n0) =
            make_float2(x0, x1);

        float s0 = fast_sigmoid(x0);
        float s1 = fast_sigmoid(x1);
        int c;
        asm("v_cvt_pk_bf16_f32 %0, %1, %2" : "=v"(c) : "v"(s0), "v"(s1));
        *(int*)((void*)(sbuf + ((size_t)b * tc + tl) * NDIM + n0)) = c;

        // rotate u ring, load 3 ahead
        uv = q0; q0 = q1;
        const int tn = (tl + 3 < tc) ? (tl + 3) : (tc - 1);
        q1 = *(const float2*)(u + ((size_t)tn * BTRIALS + b) * NDIM + n0);
        psa = npa; psb = npb;
    }
}

// ---------------------------------------------------------------------------
// Phase 3: y = s @ W^T via bf16 MFMA 16x16x32, pure loads + MFMA. Unchanged.
// ---------------------------------------------------------------------------
__global__ __launch_bounds__(256) void y_gemm(const unsigned short* __restrict__ sbuf,
                                              const unsigned short* __restrict__ Wb,
                                              float* __restrict__ yout,
                                              int t0, int tc) {
    const int tid  = threadIdx.x;
    const int lane = tid & 63;
    const int mt   = blockIdx.x * 4 + (tid >> 6);
    const int lm   = lane & 15;
    const int kq   = lane >> 4;

    const int tilesPerB = tc >> 4;
    const int b  = mt / tilesPerB;
    const int tt = mt % tilesPerB;

    const unsigned short* pa = sbuf + ((size_t)b * tc + tt * 16 + lm) * NDIM + kq * 8;
    const unsigned short* pw = Wb + (size_t)lm * NDIM + kq * 8;

    v4f acc[4];
    #pragma unroll
    for (int ot = 0; ot < 4; ++ot) acc[ot] = (v4f){0.f, 0.f, 0.f, 0.f};

    #pragma unroll 4
    for (int kc = 0; kc < NDIM; kc += 32) {
        v8s af = *(const v8s*)(pa + kc);
        #pragma unroll
        for (int ot = 0; ot < 4; ++ot) {
            v8s bf = *(const v8s*)(pw + (size_t)ot * 16 * NDIM + kc);
            acc[ot] = __builtin_amdgcn_mfma_f32_16x16x32_bf16(af, bf, acc[ot], 0, 0, 0);
        }
    }

    #pragma unroll
    for (int ot = 0; ot < 4; ++ot) {
        #pragma unroll
        for (int r = 0; r < 4; ++r) {
            const int row = b * TSTEPS + t0 + tt * 16 + kq * 4 + r;
            yout[(size_t)row * ODIM + ot * 16 + lm] = acc[ot][r];
        }
    }
}

extern "C" void kernel_launch(void* const* d_in, const int* in_sizes, int n_in,
                              void* d_out, int out_size, void* d_ws, size_t ws_size,
                              hipStream_t stream) {
    const float* inp = (const float*)d_in[0];   // [32][512][64]
    const float* Bm  = (const float*)d_in[1];   // [4096][64]
    const float* Wm  = (const float*)d_in[2];   // [64][4096]
    const float* mm  = (const float*)d_in[3];   // [4096][8]
    const float* nm  = (const float*)d_in[4];   // [4096][8]

    float* out  = (float*)d_out;
    float* xseq = out;                                          // [32][513][4096]
    float* yout = out + (size_t)BTRIALS * (TSTEPS + 1) * NDIM;  // [32][512][64]

    // ws: xstate | Wb | Ah | Al | Bh | Bl | psbuf | ubuf fp32 | sbuf bf16
    float* xstate      = (float*)d_ws;                                       // 512 KB
    unsigned short* Wb = (unsigned short*)(xstate + (size_t)BTRIALS * NDIM); // 512 KB
    unsigned short* Ah = Wb + (size_t)ODIM * NDIM;                           // 2 MB
    unsigned short* Al = Ah + (size_t)BTRIALS * TSTEPS * IDIM;               // 2 MB
    unsigned short* Bh = Al + (size_t)BTRIALS * TSTEPS * IDIM;               // 512 KB
    unsigned short* Bl = Bh + (size_t)NDIM * IDIM;                           // 512 KB
    float* psbuf       = (float*)(Bl + (size_t)NDIM * IDIM);                 // 512 KB
    float* ubuf        = psbuf + (size_t)BTRIALS * TSTEPS * RDIM;

    const size_t head = (size_t)((char*)ubuf - (char*)d_ws);
    const size_t perstep = (size_t)BTRIALS * NDIM * (sizeof(float) + sizeof(unsigned short));
    size_t avail = (ws_size > head) ? (ws_size - head) : 0;
    int Tc = (int)(avail / perstep);
    if (Tc > TSTEPS) Tc = TSTEPS;
    Tc &= ~15;                      // multiple of 16 for y_gemm tiling
    if (Tc < 16) Tc = 16;

    wconv<<<(ODIM * NDIM) / (256 * 8), 256, 0, stream>>>(Wm, Wb);
    split_conv<<<(BTRIALS * TSTEPS * IDIM) / (256 * 8), 256, 0, stream>>>(inp, Ah, Al, 0.1f);
    split_conv<<<(NDIM * IDIM) / (256 * 8), 256, 0, stream>>>(Bm, Bh, Bl, 1.0f);

    for (int t0 = 0; t0 < TSTEPS; t0 += Tc) {
        const int tc = (TSTEPS - t0 < Tc) ? (TSTEPS - t0) : Tc;
        unsigned short* sbuf = (unsigned short*)(ubuf + (size_t)tc * BTRIALS * NDIM);
        const int rows = tc * BTRIALS;
        pre_gemm_mfma<<<rows / 16, 256, 0, stream>>>(Ah, Al, Bh, Bl, ubuf, t0);
        scan_kernel<<<BTRIALS, 512, 0, stream>>>(mm, nm, ubuf, xstate, psbuf, t0, tc);
        x_replay<<<dim3(8, BTRIALS), 256, 0, stream>>>(mm, ubuf, psbuf, xseq, sbuf, t0, tc);
        const int mtiles = BTRIALS * (tc / 16);
        y_gemm<<<mtiles / 4, 256, 0, stream>>>(sbuf, Wb, yout, t0, tc);
    }
}

// Round 8
// 1071.442 us; speedup vs baseline: 1.2093x; 1.2093x over previous
//
#include <hip/hip_runtime.h>

static constexpr int BTRIALS = 32;
static constexpr int TSTEPS  = 512;
static constexpr int IDIM    = 64;
static constexpr int NDIM    = 4096;
static constexpr int RDIM    = 8;
static constexpr int ODIM    = 64;

typedef short v8s __attribute__((ext_vector_type(8)));
typedef float v4f __attribute__((ext_vector_type(4)));

__device__ __forceinline__ float fast_sigmoid(float x) {
    float e = __builtin_amdgcn_exp2f(x * -1.44269504088896340736f);
    return __builtin_amdgcn_rcpf(1.0f + e);
}

// packed dual-FP32 fma: d = a*b + c on both 32-bit halves (VOP3P)
__device__ __forceinline__ float2 pk_fma(float2 a, float2 b, float2 c) {
    float2 d;
    asm("v_pk_fma_f32 %0, %1, %2, %3" : "=v"(d) : "v"(a), "v"(b), "v"(c));
    return d;
}

// v += dpp_move(v), 0-fill invalid lanes
template <int CTRL, int RMASK>
__device__ __forceinline__ float dpp_add(float v) {
    int moved = __builtin_amdgcn_update_dpp(0, __float_as_int(v), CTRL, RMASK, 0xf, true);
    return v + __int_as_float(moved);
}

// full 64-lane sum -> valid in lane 63
__device__ __forceinline__ float wave_reduce_to_lane63(float v) {
    v = dpp_add<0x111, 0xf>(v);  // row_shr:1
    v = dpp_add<0x112, 0xf>(v);  // row_shr:2
    v = dpp_add<0x114, 0xf>(v);  // row_shr:4
    v = dpp_add<0x118, 0xf>(v);  // row_shr:8
    v = dpp_add<0x142, 0xa>(v);  // row_bcast:15 -> rows 1,3
    v = dpp_add<0x143, 0xc>(v);  // row_bcast:31 -> rows 2,3
    return v;
}

__device__ __forceinline__ short f2bf(float f) {
    unsigned u = __float_as_uint(f);
    u += 0x7FFFu + ((u >> 16) & 1u);   // RNE
    return (short)(u >> 16);
}

// ---------------------------------------------------------------------------
// Split fp32 stream into bf16 hi/lo pair (optionally pre-scaled).
// ---------------------------------------------------------------------------
__global__ __launch_bounds__(256) void split_conv(const float* __restrict__ src,
                                                  unsigned short* __restrict__ hi,
                                                  unsigned short* __restrict__ lo,
                                                  float scale) {
    const int base = (blockIdx.x * 256 + threadIdx.x) * 8;
    float4 a = *(const float4*)(src + base);
    float4 b = *(const float4*)(src + base + 4);
    float v[8] = {a.x, a.y, a.z, a.w, b.x, b.y, b.z, b.w};
    v8s h, l;
    #pragma unroll
    for (int j = 0; j < 8; ++j) {
        float f  = v[j] * scale;
        short hb = f2bf(f);
        h[j] = hb;
        float fh = __uint_as_float(((unsigned)(unsigned short)hb) << 16);
        l[j] = f2bf(f - fh);
    }
    *(v8s*)(hi + base) = h;
    *(v8s*)(lo + base) = l;
}

// ---------------------------------------------------------------------------
// W fp32 -> bf16, once.
// ---------------------------------------------------------------------------
__global__ __launch_bounds__(256) void wconv(const float* __restrict__ W,
                                             unsigned short* __restrict__ Wb) {
    const int base = (blockIdx.x * 256 + threadIdx.x) * 8;
    float4 a = *(const float4*)(W + base);
    float4 b = *(const float4*)(W + base + 4);
    v8s o;
    o[0] = f2bf(a.x); o[1] = f2bf(a.y); o[2] = f2bf(a.z); o[3] = f2bf(a.w);
    o[4] = f2bf(b.x); o[5] = f2bf(b.y); o[6] = f2bf(b.z); o[7] = f2bf(b.w);
    *(v8s*)(Wb + base) = o;
}

// ---------------------------------------------------------------------------
// Phase 1 (MFMA): u = (DT*inp) @ B^T via bf16x3 split arithmetic. Unchanged.
// ---------------------------------------------------------------------------
__global__ __launch_bounds__(256) void pre_gemm_mfma(const unsigned short* __restrict__ Ah,
                                                     const unsigned short* __restrict__ Al,
                                                     const unsigned short* __restrict__ Bh,
                                                     const unsigned short* __restrict__ Bl,
                                                     float* __restrict__ u, int t0) {
    const int tid  = threadIdx.x;
    const int lane = tid & 63;
    const int wv   = tid >> 6;          // 0..3
    const int lm   = lane & 15;
    const int kq   = lane >> 4;         // 0..3

    const int mloc = blockIdx.x * 16 + lm;        // u row (tl*32+b)
    const int b    = mloc & 31;
    const int t    = t0 + (mloc >> 5);
    const size_t arow = (size_t)b * TSTEPS + t;

    const unsigned short* pah = Ah + arow * IDIM + kq * 8;
    const unsigned short* pal = Al + arow * IDIM + kq * 8;
    v8s ah0 = *(const v8s*)(pah);
    v8s ah1 = *(const v8s*)(pah + 32);
    v8s al0 = *(const v8s*)(pal);
    v8s al1 = *(const v8s*)(pal + 32);

    const int n0   = wv * 1024;
    const int urow = blockIdx.x * 16 + kq * 4;

    #pragma unroll 2
    for (int nt = 0; nt < 64; ++nt) {
        const int n = n0 + nt * 16 + lm;
        const unsigned short* pbh = Bh + (size_t)n * IDIM + kq * 8;
        const unsigned short* pbl = Bl + (size_t)n * IDIM + kq * 8;
        v8s bh0 = *(const v8s*)(pbh);
        v8s bh1 = *(const v8s*)(pbh + 32);
        v8s bl0 = *(const v8s*)(pbl);
        v8s bl1 = *(const v8s*)(pbl + 32);
        v4f acc = (v4f){0.f, 0.f, 0.f, 0.f};
        acc = __builtin_amdgcn_mfma_f32_16x16x32_bf16(ah0, bl0, acc, 0, 0, 0);
        acc = __builtin_amdgcn_mfma_f32_16x16x32_bf16(al0, bh0, acc, 0, 0, 0);
        acc = __builtin_amdgcn_mfma_f32_16x16x32_bf16(ah1, bl1, acc, 0, 0, 0);
        acc = __builtin_amdgcn_mfma_f32_16x16x32_bf16(al1, bh1, acc, 0, 0, 0);
        acc = __builtin_amdgcn_mfma_f32_16x16x32_bf16(ah0, bh0, acc, 0, 0, 0);
        acc = __builtin_amdgcn_mfma_f32_16x16x32_bf16(ah1, bh1, acc, 0, 0, 0);
        float* up = u + (size_t)urow * NDIM + n0 + nt * 16 + lm;
        #pragma unroll
        for (int r = 0; r < 4; ++r) up[(size_t)r * NDIM] = acc[r];
    }
}

// ---------------------------------------------------------------------------
// Phase 2: serial scan, direct writes restored (writes are ~free; r0/r1/r6
// A/B). VALU issue cut via v_pk_fma_f32 on the two 64-FMA blocks.
// 32 blocks x 512 threads, 8 n/thread (4 float2 pairs).
// ---------------------------------------------------------------------------
__global__ __launch_bounds__(512, 2) void scan_kernel(const float* __restrict__ mmat,
                                                      const float* __restrict__ nmat,
                                                      const float* __restrict__ u,
                                                      float* __restrict__ xseq,
                                                      float* __restrict__ xstate,
                                                      unsigned short* __restrict__ sbuf,
                                                      int t0, int tc) {
    const int b    = blockIdx.x;
    const int tid  = threadIdx.x;
    const int j0   = tid * 8;
    const int lane = tid & 63;
    const int wv   = tid >> 6;   // 0..7

    __shared__ __align__(16) float wlds[2][64];   // [r*8 + w], double-buffered

    // packed over j-pairs: nmp[jp][r] = {nm[2jp][r], nm[2jp+1][r]}
    float2 nmp[4][8], mmp[4][8], x2[4], sp[4];
    const float mscale = 0.1f / 4096.0f;   // DT / N folded into m
    #pragma unroll
    for (int jp = 0; jp < 4; ++jp) {
        const float4* na = (const float4*)(nmat + (size_t)(j0 + 2 * jp) * RDIM);
        float4 a0 = na[0], a1 = na[1], b0 = na[2], b1 = na[3];
        nmp[jp][0] = {a0.x, b0.x}; nmp[jp][1] = {a0.y, b0.y};
        nmp[jp][2] = {a0.z, b0.z}; nmp[jp][3] = {a0.w, b0.w};
        nmp[jp][4] = {a1.x, b1.x}; nmp[jp][5] = {a1.y, b1.y};
        nmp[jp][6] = {a1.z, b1.z}; nmp[jp][7] = {a1.w, b1.w};
        const float4* ma = (const float4*)(mmat + (size_t)(j0 + 2 * jp) * RDIM);
        float4 d0 = ma[0], d1 = ma[1], e0 = ma[2], e1 = ma[3];
        mmp[jp][0] = {d0.x * mscale, e0.x * mscale}; mmp[jp][1] = {d0.y * mscale, e0.y * mscale};
        mmp[jp][2] = {d0.z * mscale, e0.z * mscale}; mmp[jp][3] = {d0.w * mscale, e0.w * mscale};
        mmp[jp][4] = {d1.x * mscale, e1.x * mscale}; mmp[jp][5] = {d1.y * mscale, e1.y * mscale};
        mmp[jp][6] = {d1.z * mscale, e1.z * mscale}; mmp[jp][7] = {d1.w * mscale, e1.w * mscale};
    }

    if (t0 == 0) {
        #pragma unroll
        for (int jp = 0; jp < 4; ++jp) x2[jp] = {0.f, 0.f};
        float* z = xseq + (size_t)b * (TSTEPS + 1) * NDIM + j0;
        *(float4*)(z + 0) = make_float4(0.f, 0.f, 0.f, 0.f);
        *(float4*)(z + 4) = make_float4(0.f, 0.f, 0.f, 0.f);
    } else {
        const float* xs = xstate + (size_t)b * NDIM + j0;
        float4 v0 = *(const float4*)(xs + 0);
        float4 v1 = *(const float4*)(xs + 4);
        x2[0] = {v0.x, v0.y}; x2[1] = {v0.z, v0.w};
        x2[2] = {v1.x, v1.y}; x2[3] = {v1.z, v1.w};
    }
    #pragma unroll
    for (int jp = 0; jp < 4; ++jp)
        sp[jp] = {fast_sigmoid(x2[jp].x), fast_sigmoid(x2[jp].y)};

    float2 uvp[4];
    {
        const float* up = u + ((size_t)0 * BTRIALS + b) * NDIM + j0;
        float4 v0 = *(const float4*)(up + 0);
        float4 v1 = *(const float4*)(up + 4);
        uvp[0] = {v0.x, v0.y}; uvp[1] = {v0.z, v0.w};
        uvp[2] = {v1.x, v1.y}; uvp[3] = {v1.z, v1.w};
    }
    const float2 c09 = {0.9f, 0.9f};

    for (int tl = 0; tl < tc; ++tl) {
        const int buf = tl & 1;
        // prefetch u for next step
        const int tn = (tl + 1 < tc) ? (tl + 1) : tl;
        const float* upn = u + ((size_t)tn * BTRIALS + b) * NDIM + j0;
        float4 pf0 = *(const float4*)(upn + 0);
        float4 pf1 = *(const float4*)(upn + 4);

        // packed partial projections
        float2 p2[8];
        #pragma unroll
        for (int r = 0; r < 8; ++r) p2[r] = {0.f, 0.f};
        #pragma unroll
        for (int jp = 0; jp < 4; ++jp) {
            #pragma unroll
            for (int r = 0; r < 8; ++r) p2[r] = pk_fma(sp[jp], nmp[jp][r], p2[r]);
        }
        float part[8];
        #pragma unroll
        for (int r = 0; r < 8; ++r) part[r] = p2[r].x + p2[r].y;
        #pragma unroll
        for (int r = 0; r < 8; ++r) part[r] = wave_reduce_to_lane63(part[r]);

        if (lane == 63) {
            #pragma unroll
            for (int r = 0; r < 8; ++r) wlds[buf][r * 8 + wv] = part[r];
        }

        // decay + input (packed) before the barrier
        float2 xd2[4];
        #pragma unroll
        for (int jp = 0; jp < 4; ++jp) xd2[jp] = pk_fma(c09, x2[jp], uvp[jp]);

        __syncthreads();

        // fold 8 wave-partials per r
        float v = wlds[buf][lane];
        v = dpp_add<0x111, 0xf>(v);  // row_shr:1
        v = dpp_add<0x112, 0xf>(v);  // row_shr:2
        v = dpp_add<0x114, 0xf>(v);  // row_shr:4

        float ps[8];
        #pragma unroll
        for (int r = 0; r < 8; ++r)
            ps[r] = __int_as_float(__builtin_amdgcn_readlane(__float_as_int(v), r * 8 + 7));

        // packed x update
        #pragma unroll
        for (int r = 0; r < 8; ++r) {
            float2 psr = {ps[r], ps[r]};
            #pragma unroll
            for (int jp = 0; jp < 4; ++jp) xd2[jp] = pk_fma(psr, mmp[jp][r], xd2[jp]);
        }
        #pragma unroll
        for (int jp = 0; jp < 4; ++jp) x2[jp] = xd2[jp];

        float* xrow = xseq + ((size_t)b * (TSTEPS + 1) + (t0 + tl + 1)) * NDIM + j0;
        *(float4*)(xrow + 0) = make_float4(x2[0].x, x2[0].y, x2[1].x, x2[1].y);
        *(float4*)(xrow + 4) = make_float4(x2[2].x, x2[2].y, x2[3].x, x2[3].y);

        // next-step sigmoid; emit bf16 via packed converts
        #pragma unroll
        for (int jp = 0; jp < 4; ++jp)
            sp[jp] = {fast_sigmoid(x2[jp].x), fast_sigmoid(x2[jp].y)};
        int c0, c1, c2, c3;
        asm("v_cvt_pk_bf16_f32 %0, %1, %2" : "=v"(c0) : "v"(sp[0].x), "v"(sp[0].y));
        asm("v_cvt_pk_bf16_f32 %0, %1, %2" : "=v"(c1) : "v"(sp[1].x), "v"(sp[1].y));
        asm("v_cvt_pk_bf16_f32 %0, %1, %2" : "=v"(c2) : "v"(sp[2].x), "v"(sp[2].y));
        asm("v_cvt_pk_bf16_f32 %0, %1, %2" : "=v"(c3) : "v"(sp[3].x), "v"(sp[3].y));
        *(int4*)((void*)(sbuf + ((size_t)b * tc + tl) * NDIM + j0)) = make_int4(c0, c1, c2, c3);

        uvp[0] = {pf0.x, pf0.y}; uvp[1] = {pf0.z, pf0.w};
        uvp[2] = {pf1.x, pf1.y}; uvp[3] = {pf1.z, pf1.w};
    }

    float* xs = xstate + (size_t)b * NDIM + j0;
    *(float4*)(xs + 0) = make_float4(x2[0].x, x2[0].y, x2[1].x, x2[1].y);
    *(float4*)(xs + 4) = make_float4(x2[2].x, x2[2].y, x2[3].x, x2[3].y);
}

// ---------------------------------------------------------------------------
// Phase 3: y = s @ W^T via bf16 MFMA. Occupancy-doubled: each wave handles
// one 16-row m-tile x TWO o-tiles -> 2048 waves (2/SIMD) instead of 1024.
// ---------------------------------------------------------------------------
__global__ __launch_bounds__(256) void y_gemm(const unsigned short* __restrict__ sbuf,
                                              const unsigned short* __restrict__ Wb,
                                              float* __restrict__ yout,
                                              int t0, int tc) {
    const int tid  = threadIdx.x;
    const int lane = tid & 63;
    const int w    = blockIdx.x * 4 + (tid >> 6);   // wave task id
    const int mt   = w >> 1;                        // m-tile (16 rows)
    const int ob   = (w & 1) << 1;                  // o-tile base: 0 or 2
    const int lm   = lane & 15;
    const int kq   = lane >> 4;                     // 0..3

    const int tilesPerB = tc >> 4;
    const int b  = mt / tilesPerB;
    const int tt = mt % tilesPerB;

    const unsigned short* pa = sbuf + ((size_t)b * tc + tt * 16 + lm) * NDIM + kq * 8;
    const unsigned short* pw0 = Wb + (size_t)(ob * 16 + lm) * NDIM + kq * 8;
    const unsigned short* pw1 = pw0 + (size_t)16 * NDIM;

    v4f acc0 = (v4f){0.f, 0.f, 0.f, 0.f};
    v4f acc1 = (v4f){0.f, 0.f, 0.f, 0.f};

    #pragma unroll 4
    for (int kc = 0; kc < NDIM; kc += 32) {
        v8s af = *(const v8s*)(pa + kc);
        v8s bf0 = *(const v8s*)(pw0 + kc);
        v8s bf1 = *(const v8s*)(pw1 + kc);
        acc0 = __builtin_amdgcn_mfma_f32_16x16x32_bf16(af, bf0, acc0, 0, 0, 0);
        acc1 = __builtin_amdgcn_mfma_f32_16x16x32_bf16(af, bf1, acc1, 0, 0, 0);
    }

    #pragma unroll
    for (int r = 0; r < 4; ++r) {
        const int row = b * TSTEPS + t0 + tt * 16 + kq * 4 + r;
        yout[(size_t)row * ODIM + (ob + 0) * 16 + lm] = acc0[r];
        yout[(size_t)row * ODIM + (ob + 1) * 16 + lm] = acc1[r];
    }
}

extern "C" void kernel_launch(void* const* d_in, const int* in_sizes, int n_in,
                              void* d_out, int out_size, void* d_ws, size_t ws_size,
                              hipStream_t stream) {
    const float* inp = (const float*)d_in[0];   // [32][512][64]
    const float* Bm  = (const float*)d_in[1];   // [4096][64]
    const float* Wm  = (const float*)d_in[2];   // [64][4096]
    const float* mm  = (const float*)d_in[3];   // [4096][8]
    const float* nm  = (const float*)d_in[4];   // [4096][8]

    float* out  = (float*)d_out;
    float* xseq = out;                                          // [32][513][4096]
    float* yout = out + (size_t)BTRIALS * (TSTEPS + 1) * NDIM;  // [32][512][64]

    // ws: xstate | Wb | Ah | Al | Bh | Bl | ubuf fp32 | sbuf bf16
    float* xstate      = (float*)d_ws;                                       // 512 KB
    unsigned short* Wb = (unsigned short*)(xstate + (size_t)BTRIALS * NDIM); // 512 KB
    unsigned short* Ah = Wb + (size_t)ODIM * NDIM;                           // 2 MB
    unsigned short* Al = Ah + (size_t)BTRIALS * TSTEPS * IDIM;               // 2 MB
    unsigned short* Bh = Al + (size_t)BTRIALS * TSTEPS * IDIM;               // 512 KB
    unsigned short* Bl = Bh + (size_t)NDIM * IDIM;                           // 512 KB
    float* ubuf        = (float*)(Bl + (size_t)NDIM * IDIM);

    const size_t head = (size_t)((char*)ubuf - (char*)d_ws);
    const size_t perstep = (size_t)BTRIALS * NDIM * (sizeof(float) + sizeof(unsigned short));
    size_t avail = (ws_size > head) ? (ws_size - head) : 0;
    int Tc = (int)(avail / perstep);
    if (Tc > TSTEPS) Tc = TSTEPS;
    Tc &= ~15;                      // multiple of 16 for y_gemm tiling
    if (Tc < 16) Tc = 16;

    wconv<<<(ODIM * NDIM) / (256 * 8), 256, 0, stream>>>(Wm, Wb);
    split_conv<<<(BTRIALS * TSTEPS * IDIM) / (256 * 8), 256, 0, stream>>>(inp, Ah, Al, 0.1f);
    split_conv<<<(NDIM * IDIM) / (256 * 8), 256, 0, stream>>>(Bm, Bh, Bl, 1.0f);

    for (int t0 = 0; t0 < TSTEPS; t0 += Tc) {
        const int tc = (TSTEPS - t0 < Tc) ? (TSTEPS - t0) : Tc;
        unsigned short* sbuf = (unsigned short*)(ubuf + (size_t)tc * BTRIALS * NDIM);
        const int rows = tc * BTRIALS;
        pre_gemm_mfma<<<rows / 16, 256, 0, stream>>>(Ah, Al, Bh, Bl, ubuf, t0);
        scan_kernel<<<BTRIALS, 512, 0, stream>>>(mm, nm, ubuf, xseq, xstate, sbuf, t0, tc);
        const int mtiles = BTRIALS * (tc / 16);
        y_gemm<<<mtiles / 2, 256, 0, stream>>>(sbuf, Wb, yout, t0, tc);
    }
}